// Round 1
// 302.410 us; speedup vs baseline: 1.0231x; 1.0231x over previous
//
#include <hip/hip_runtime.h>
#include <hip/hip_bf16.h>

// GCNEncoder: 2-layer GCN, out-degree norm. N=100000, E=1600000, 128->128->64, fp32 I/O.
// R10: aggregates are latency-bound (VALUBusy 36.6%, hbm 44%, VGPR=24 -> only 4 gathers in
// flight, no SW pipelining). Double MLP: 8-edge unrolled gather loop with int4 index prefetch.
// Kill the divergent scalar tail: pad slots in each 4-aligned segment are filled with dummy
// index N pointing at a zeroed row (row N of h/g, zeroed by the GEMM kernels), so aggregation
// is pure 4/8-groups. g aliased onto dead `pairs` buffer to host the extra row.
// Predict: aggregate128 58.6 -> ~38us, VALUBusy -> ~55-60%, FETCH flat; total 309 -> ~255us.

typedef __attribute__((ext_vector_type(8))) short short8;
typedef __attribute__((ext_vector_type(4))) float floatx4;

__device__ inline unsigned short f2bf(float f) {
    union { float f; unsigned u; } v; v.f = f;
    unsigned r = v.u + 0x7FFF + ((v.u >> 16) & 1);  // RNE
    return (unsigned short)(r >> 16);
}
__device__ inline float bf2f(unsigned b) {
    union { unsigned u; float f; } v; v.u = b << 16;
    return v.f;
}
__device__ inline float bf2f_hi(unsigned b) {
    union { unsigned u; float f; } v; v.u = b & 0xFFFF0000u;
    return v.f;
}

#define NBMAX 512   // max 256-node buckets -> N <= 131072 (src < 2^24 for packing)
#define CAP   8192  // fixed bucket capacity; mean 4092 + <=768 alignment pad -> safe

// ---- W preconvert fp32[k][n] -> bf16[n][k] for both layers; also zeros bucket cursors ----
__global__ __launch_bounds__(256) void convw_kernel(
    const float* __restrict__ W1, const float* __restrict__ W2,
    unsigned short* __restrict__ Wb1, unsigned short* __restrict__ Wb2,
    int* __restrict__ cnt)
{
    int i = blockIdx.x * 256 + threadIdx.x;
    if (i < NBMAX * 32) cnt[i] = 0;  // cnt_d | cnt_s (2 * NBMAX * 16 ints)
    if (i < 128 * 128) {
        int k = i >> 7, n = i & 127;
        Wb1[n * 128 + k] = f2bf(W1[k * 128 + n]);
    }
    i -= 128 * 128;
    if (i >= 0 && i < 128 * 64) {
        int k = i >> 6, n = i & 63;
        Wb2[n * 128 + k] = f2bf(W2[k * 64 + n]);
    }
}

// ---- pass 1: LDS bucket histograms -> reserve runs via global cursors -> scatter ----
__global__ __launch_bounds__(256) void scatter2_kernel(
    const int* __restrict__ src, const int* __restrict__ dst, int E,
    int* __restrict__ cnt_d, int* __restrict__ cnt_s,   // stride-16 padded cursors
    unsigned* __restrict__ pairs, unsigned char* __restrict__ srcs_b, int NB)
{
    __shared__ int hd[NBMAX], bd[NBMAX], cd_[NBMAX];
    __shared__ int hs[NBMAX], bs[NBMAX], cs_[NBMAX];
    for (int i = threadIdx.x; i < NB; i += 256) { hd[i] = 0; cd_[i] = 0; hs[i] = 0; cs_[i] = 0; }
    __syncthreads();
    const int e0 = blockIdx.x * 8192;
    const int e1 = min(e0 + 8192, E);
    for (int i = e0 + threadIdx.x; i < e1; i += 256) {
        atomicAdd(&hd[dst[i] >> 8], 1);
        atomicAdd(&hs[src[i] >> 8], 1);
    }
    __syncthreads();
    for (int i = threadIdx.x; i < NB; i += 256) {
        if (hd[i]) bd[i] = atomicAdd(&cnt_d[i * 16], hd[i]);
        if (hs[i]) bs[i] = atomicAdd(&cnt_s[i * 16], hs[i]);
    }
    __syncthreads();
    for (int i = e0 + threadIdx.x; i < e1; i += 256) {
        int sv = src[i], dv = dst[i];
        int b = dv >> 8;
        int slot = atomicAdd(&cd_[b], 1);
        pairs[(size_t)b * CAP + bd[b] + slot] = ((unsigned)(dv & 255) << 24) | (unsigned)sv;
        int b2 = sv >> 8;
        int slot2 = atomicAdd(&cs_[b2], 1);
        srcs_b[(size_t)b2 * CAP + bs[b2] + slot2] = (unsigned char)(sv & 255);
    }
}

// ---- pass 2 (fused): per-bucket dst sort (4-aligned segment starts, pads filled with dummy
//      index N -> zero row) -> sorted_src + (start,end) per node; src hist -> deg_inv ----
__global__ __launch_bounds__(256) void bucket_finalize_kernel(
    const unsigned* __restrict__ pairs, const unsigned char* __restrict__ srcs_b,
    const int* __restrict__ cnt_d, const int* __restrict__ cnt_s,
    int* __restrict__ sorted_src, int2* __restrict__ se,
    float* __restrict__ deg_inv, int N)
{
    const int b = blockIdx.x;
    const int node0 = b << 8;
    const int t = threadIdx.x;
    const size_t base = (size_t)b * CAP;
    __shared__ int hist[256];
    __shared__ int cur[256];
    __shared__ int pre[256];

    const int cd = cnt_d[b * 16];
    hist[t] = 0;
    __syncthreads();
    for (int i = t; i < cd; i += 256)
        atomicAdd(&hist[pairs[base + i] >> 24], 1);
    __syncthreads();
    int v = hist[t];
    int v4 = (v + 3) & ~3;  // 4-edge aligned segments (16B int4 idx loads)
    pre[t] = v4;
    __syncthreads();
    for (int o = 1; o < 256; o <<= 1) {
        int add = (t >= o) ? pre[t - o] : 0;
        __syncthreads();
        pre[t] += add;
        __syncthreads();
    }
    int excl = pre[t] - v4;
    cur[t] = excl;
    if (node0 + t < N) {
        se[node0 + t] = make_int2((int)base + excl, (int)base + excl + v);
        // fill alignment pad with dummy index N (zero row) -> aggregates need no scalar tail
        for (int i = v; i < v4; ++i) sorted_src[base + excl + i] = N;
    }
    __syncthreads();
    for (int i = t; i < cd; i += 256) {
        unsigned p = pairs[base + i];
        int pos = atomicAdd(&cur[p >> 24], 1);
        sorted_src[base + pos] = (int)(p & 0xFFFFFFu);
    }

    __syncthreads();
    hist[t] = 0;
    __syncthreads();
    const int cs = cnt_s[b * 16];
    for (int i = t; i < cs; i += 256)
        atomicAdd(&hist[srcs_b[base + i]], 1);
    __syncthreads();
    if (node0 + t < N) {
        int d = hist[t];
        deg_inv[node0 + t] = 1.0f / (float)(d < 1 ? 1 : d);
    }
}

// ---------------- MFMA GEMM, no LDS: per-lane A fragments straight from global ----------------
// 64 rows/block (4 waves x 16 rows). AF=1: A fp32, scale (deg_inv) applied in epilogue.
// AF=0: A bf16 already scaled. B = bf16 Wb[n][k], L1/L2-resident.
// Block 0 additionally zeroes output row M (the dummy row read by aggregation pads).
template <int NC, int AF>
__global__ __launch_bounds__(256) void gemm_mfma_kernel(
    const void* __restrict__ Ap, const unsigned short* __restrict__ Wb,
    const float* __restrict__ scale, unsigned short* __restrict__ Cb, int M)
{
    constexpr int NT = NC / 16;
    const int t = threadIdx.x;
    if (blockIdx.x == 0 && t < NC / 2)
        ((unsigned*)Cb)[(size_t)M * (NC / 2) + t] = 0;  // zero dummy row M
    const int wm = t >> 6;
    const int lane = t & 63;
    const int lm = lane & 15;
    const int lk = (lane >> 4) * 8;

    const int r0 = blockIdx.x * 64 + wm * 16;
    int row = r0 + lm;
    if (row >= M) row = M - 1;  // clamp loads; stores are guarded

    floatx4 acc[NT];
#pragma unroll
    for (int j = 0; j < NT; ++j) acc[j] = (floatx4){0.f, 0.f, 0.f, 0.f};

#pragma unroll
    for (int kk = 0; kk < 4; ++kk) {
        const int kb = kk * 32 + lk;
        short8 af;
        if (AF) {
            const float* arow = (const float*)Ap + (size_t)row * 128 + kb;
            float4 a0 = *(const float4*)arow;
            float4 a1 = *(const float4*)(arow + 4);
            af[0] = (short)f2bf(a0.x); af[1] = (short)f2bf(a0.y);
            af[2] = (short)f2bf(a0.z); af[3] = (short)f2bf(a0.w);
            af[4] = (short)f2bf(a1.x); af[5] = (short)f2bf(a1.y);
            af[6] = (short)f2bf(a1.z); af[7] = (short)f2bf(a1.w);
        } else {
            af = *(const short8*)&((const unsigned short*)Ap)[(size_t)row * 128 + kb];
        }
#pragma unroll
        for (int j = 0; j < NT; ++j) {
            short8 bfr = *(const short8*)&Wb[(size_t)(j * 16 + lm) * 128 + kb];
            acc[j] = __builtin_amdgcn_mfma_f32_16x16x32_bf16(af, bfr, acc[j], 0, 0, 0);
        }
    }

    const int rbase = r0 + (lane >> 4) * 4;
#pragma unroll
    for (int reg = 0; reg < 4; ++reg) {
        int rg = rbase + reg;
        if (rg < M) {
            float di = AF ? scale[rg] : 1.0f;
#pragma unroll
            for (int j = 0; j < NT; ++j)
                Cb[(size_t)rg * NC + j * 16 + lm] = f2bf(AF ? acc[j][reg] * di : acc[j][reg]);
        }
    }
}

// ---------------- aggregate C=128: half-wave/node, uint2 loads, 8-edge unroll + idx prefetch ----------------
// Epilogue: relu(. + b1) * deg_inv -> bf16 (deg_inv of NEXT layer's row folded here).
#define LD128(vv, ii) uint2 vv = *(const uint2*)&val[(size_t)(ii) * 64 + 2 * l]
#define ACC8_128(I0, I1) do { \
    LD128(v0, I0.x); LD128(v1, I0.y); LD128(v2, I0.z); LD128(v3, I0.w); \
    LD128(v4, I1.x); LD128(v5, I1.y); LD128(v6, I1.z); LD128(v7, I1.w); \
    a0 += ((bf2f(v0.x & 0xFFFF) + bf2f(v1.x & 0xFFFF)) + (bf2f(v2.x & 0xFFFF) + bf2f(v3.x & 0xFFFF))) \
        + ((bf2f(v4.x & 0xFFFF) + bf2f(v5.x & 0xFFFF)) + (bf2f(v6.x & 0xFFFF) + bf2f(v7.x & 0xFFFF))); \
    a1 += ((bf2f_hi(v0.x) + bf2f_hi(v1.x)) + (bf2f_hi(v2.x) + bf2f_hi(v3.x))) \
        + ((bf2f_hi(v4.x) + bf2f_hi(v5.x)) + (bf2f_hi(v6.x) + bf2f_hi(v7.x))); \
    a2 += ((bf2f(v0.y & 0xFFFF) + bf2f(v1.y & 0xFFFF)) + (bf2f(v2.y & 0xFFFF) + bf2f(v3.y & 0xFFFF))) \
        + ((bf2f(v4.y & 0xFFFF) + bf2f(v5.y & 0xFFFF)) + (bf2f(v6.y & 0xFFFF) + bf2f(v7.y & 0xFFFF))); \
    a3 += ((bf2f_hi(v0.y) + bf2f_hi(v1.y)) + (bf2f_hi(v2.y) + bf2f_hi(v3.y))) \
        + ((bf2f_hi(v4.y) + bf2f_hi(v5.y)) + (bf2f_hi(v6.y) + bf2f_hi(v7.y))); \
} while (0)
#define ACC4_128(I0) do { \
    LD128(v0, I0.x); LD128(v1, I0.y); LD128(v2, I0.z); LD128(v3, I0.w); \
    a0 += (bf2f(v0.x & 0xFFFF) + bf2f(v1.x & 0xFFFF)) + (bf2f(v2.x & 0xFFFF) + bf2f(v3.x & 0xFFFF)); \
    a1 += (bf2f_hi(v0.x) + bf2f_hi(v1.x)) + (bf2f_hi(v2.x) + bf2f_hi(v3.x)); \
    a2 += (bf2f(v0.y & 0xFFFF) + bf2f(v1.y & 0xFFFF)) + (bf2f(v2.y & 0xFFFF) + bf2f(v3.y & 0xFFFF)); \
    a3 += (bf2f_hi(v0.y) + bf2f_hi(v1.y)) + (bf2f_hi(v2.y) + bf2f_hi(v3.y)); \
} while (0)

__global__ __launch_bounds__(256) void aggregate128_kernel(
    const int2* __restrict__ se, const int* __restrict__ sorted_src,
    const unsigned* __restrict__ val, const float* __restrict__ bias,
    const float* __restrict__ deg_inv, unsigned* __restrict__ outb, int N)
{
    int node = blockIdx.x * 8 + (threadIdx.x >> 5);
    if (node >= N) return;
    int l = threadIdx.x & 31;
    int2 r = se[node];
    int e = r.x;
    const int end4 = r.x + ((r.y - r.x + 3) & ~3);  // pads -> zero row, safe to include
    float a0 = 0.f, a1 = 0.f, a2 = 0.f, a3 = 0.f;

    if (e + 8 <= end4) {
        int4 i0 = *(const int4*)&sorted_src[e];
        int4 i1 = *(const int4*)&sorted_src[e + 4];
        for (; e + 16 <= end4; e += 8) {
            int4 n0 = *(const int4*)&sorted_src[e + 8];
            int4 n1 = *(const int4*)&sorted_src[e + 12];
            ACC8_128(i0, i1);
            i0 = n0; i1 = n1;
        }
        ACC8_128(i0, i1);
        e += 8;
    }
    if (e < end4) {  // exactly 4 remain (segment length is a multiple of 4)
        int4 i0 = *(const int4*)&sorted_src[e];
        ACC4_128(i0);
    }

    float di = deg_inv[node];
    float4 bv = *(const float4*)&bias[4 * l];
    a0 = fmaxf(a0 + bv.x, 0.f) * di;
    a1 = fmaxf(a1 + bv.y, 0.f) * di;
    a2 = fmaxf(a2 + bv.z, 0.f) * di;
    a3 = fmaxf(a3 + bv.w, 0.f) * di;
    uint2 o;
    o.x = (unsigned)f2bf(a0) | ((unsigned)f2bf(a1) << 16);
    o.y = (unsigned)f2bf(a2) | ((unsigned)f2bf(a3) << 16);
    *(uint2*)&outb[(size_t)node * 64 + 2 * l] = o;
}

// ---------------- aggregate C=64 (bf16 in, fp32 out, +bias): 8-edge unroll + idx prefetch ----------------
#define LD64(vv, ii) unsigned vv = val[(size_t)(ii) * 32 + l]
#define ACC8_64(I0, I1) do { \
    LD64(v0, I0.x); LD64(v1, I0.y); LD64(v2, I0.z); LD64(v3, I0.w); \
    LD64(v4, I1.x); LD64(v5, I1.y); LD64(v6, I1.z); LD64(v7, I1.w); \
    ax += ((bf2f(v0 & 0xFFFF) + bf2f(v1 & 0xFFFF)) + (bf2f(v2 & 0xFFFF) + bf2f(v3 & 0xFFFF))) \
        + ((bf2f(v4 & 0xFFFF) + bf2f(v5 & 0xFFFF)) + (bf2f(v6 & 0xFFFF) + bf2f(v7 & 0xFFFF))); \
    ay += ((bf2f_hi(v0) + bf2f_hi(v1)) + (bf2f_hi(v2) + bf2f_hi(v3))) \
        + ((bf2f_hi(v4) + bf2f_hi(v5)) + (bf2f_hi(v6) + bf2f_hi(v7))); \
} while (0)
#define ACC4_64(I0) do { \
    LD64(v0, I0.x); LD64(v1, I0.y); LD64(v2, I0.z); LD64(v3, I0.w); \
    ax += (bf2f(v0 & 0xFFFF) + bf2f(v1 & 0xFFFF)) + (bf2f(v2 & 0xFFFF) + bf2f(v3 & 0xFFFF)); \
    ay += (bf2f_hi(v0) + bf2f_hi(v1)) + (bf2f_hi(v2) + bf2f_hi(v3)); \
} while (0)

__global__ __launch_bounds__(256) void aggregate64_kernel(
    const int2* __restrict__ se, const int* __restrict__ sorted_src,
    const unsigned* __restrict__ val, const float* __restrict__ bias,
    float* __restrict__ out, int N)
{
    int node = blockIdx.x * 8 + (threadIdx.x >> 5);
    if (node >= N) return;
    int l = threadIdx.x & 31;
    int2 r = se[node];
    int e = r.x;
    const int end4 = r.x + ((r.y - r.x + 3) & ~3);
    float ax = 0.f, ay = 0.f;

    if (e + 8 <= end4) {
        int4 i0 = *(const int4*)&sorted_src[e];
        int4 i1 = *(const int4*)&sorted_src[e + 4];
        for (; e + 16 <= end4; e += 8) {
            int4 n0 = *(const int4*)&sorted_src[e + 8];
            int4 n1 = *(const int4*)&sorted_src[e + 12];
            ACC8_64(i0, i1);
            i0 = n0; i1 = n1;
        }
        ACC8_64(i0, i1);
        e += 8;
    }
    if (e < end4) {
        int4 i0 = *(const int4*)&sorted_src[e];
        ACC4_64(i0);
    }

    float2 o = make_float2(ax + bias[2 * l], ay + bias[2 * l + 1]);
    *(float2*)&out[(size_t)node * 64 + 2 * l] = o;
}

extern "C" void kernel_launch(void* const* d_in, const int* in_sizes, int n_in,
                              void* d_out, int out_size, void* d_ws, size_t ws_size,
                              hipStream_t stream) {
    const float* x  = (const float*)d_in[0];
    const int*   ei = (const int*)d_in[1];
    const float* W1 = (const float*)d_in[2];
    const float* b1 = (const float*)d_in[3];
    const float* W2 = (const float*)d_in[4];
    const float* b2 = (const float*)d_in[5];
    float* out = (float*)d_out;

    const int N = in_sizes[0] / 128;
    const int E = in_sizes[1] / 2;
    const int* src = ei;
    const int* dst = ei + E;
    const int NB = (N + 255) >> 8;

    char* ws = (char*)d_ws;
    size_t off = 0;
    auto alloc = [&](size_t bytes) {
        void* p = ws + off;
        off = (off + bytes + 255) & ~(size_t)255;
        return p;
    };
    float* deg_inv  = (float*)alloc((size_t)N * 4);
    int2*  se       = (int2*)alloc((size_t)N * 8);
    int*   cnt_d    = (int*)alloc((size_t)NBMAX * 16 * 4 * 2);  // cnt_d | cnt_s adjacent
    int*   cnt_s    = cnt_d + (size_t)NBMAX * 16;
    unsigned short* Wb1 = (unsigned short*)alloc((size_t)128 * 128 * 2);
    unsigned short* Wb2 = (unsigned short*)alloc((size_t)64 * 128 * 2);
    unsigned*      pairs  = (unsigned*)alloc((size_t)NBMAX * CAP * 4);
    unsigned char* srcs_b = (unsigned char*)alloc((size_t)NBMAX * CAP);
    int*   sorted_src = (int*)alloc((size_t)NBMAX * CAP * 4);
    unsigned short* h    = (unsigned short*)alloc((size_t)(N + 1) * 128 * 2);  // +1: zero pad row
    unsigned short* out1 = (unsigned short*)alloc((size_t)N * 128 * 2);
    // g ((N+1) x 64 bf16) aliases pairs (dead after bucket_finalize) when it fits
    unsigned short* g = ((size_t)(N + 1) * 128 <= (size_t)NBMAX * CAP * 4)
                            ? (unsigned short*)pairs
                            : (unsigned short*)alloc((size_t)(N + 1) * 64 * 2);

    convw_kernel<<<96, 256, 0, stream>>>(W1, W2, Wb1, Wb2, cnt_d);
    scatter2_kernel<<<(E + 8191) / 8192, 256, 0, stream>>>(src, dst, E, cnt_d, cnt_s,
                                                           pairs, srcs_b, NB);
    bucket_finalize_kernel<<<NB, 256, 0, stream>>>(pairs, srcs_b, cnt_d, cnt_s,
                                                   sorted_src, se, deg_inv, N);

    const int gblocks = (N + 63) / 64;
    // layer 1: h = bf16(di * (x @ W1)); out1 = bf16(relu(Agg(h)+b1) * di)
    gemm_mfma_kernel<128, 1><<<gblocks, 256, 0, stream>>>(x, Wb1, deg_inv, h, N);
    aggregate128_kernel<<<(N + 7) / 8, 256, 0, stream>>>(se, sorted_src, (const unsigned*)h, b1,
                                                         deg_inv, (unsigned*)out1, N);
    // layer 2: g = bf16(out1 @ W2); out = Agg(g) + b2
    gemm_mfma_kernel<64, 0><<<gblocks, 256, 0, stream>>>(out1, Wb2, nullptr, g, N);
    aggregate64_kernel<<<(N + 7) / 8, 256, 0, stream>>>(se, sorted_src, (const unsigned*)g, b2, out, N);
}